// Round 1
// baseline (398.046 us; speedup 1.0000x reference)
//
#include <hip/hip_runtime.h>
#include <hip/hip_bf16.h>
#include <stdint.h>

typedef unsigned short u16;
typedef __attribute__((ext_vector_type(8))) short s16x8;   // 8 bf16 (4 VGPRs) — MFMA A/B frag
typedef __attribute__((ext_vector_type(4))) float f32x4;   // MFMA C/D frag

#define B_   2
#define T_   2048
#define D_   1024
#define H_   16
#define HD_  64
#define DFF_ 4096
#define M_   (B_*T_)   // 4096

// ---------- helpers ----------
__device__ __forceinline__ u16 f2b(float f){          // fp32 -> bf16, RNE
  uint32_t u = __float_as_uint(f);
  u += 0x7FFFu + ((u >> 16) & 1u);
  return (u16)(u >> 16);
}
__device__ __forceinline__ float b2f(u16 u){ return __uint_as_float(((uint32_t)u) << 16); }

// async global->LDS, 16B per lane. LDS dest is wave-uniform-base + lane*16 (lane-linear).
__device__ __forceinline__ void gl_lds16(const void* g, void* l){
  __builtin_amdgcn_global_load_lds((const __attribute__((address_space(1))) void*)g,
                                   (__attribute__((address_space(3))) void*)l, 16, 0, 0);
}

// ---------- weight fp32 [K][N] -> bf16 transposed [N][K] ----------
__global__ __launch_bounds__(256) void wconv(const float* __restrict__ W, u16* __restrict__ Wt,
                                             int K, int N){
  const int k0 = blockIdx.x << 6, n0 = blockIdx.y << 6;
  __shared__ u16 tile[64][68];                 // +4 pad breaks bank conflicts on transpose read
  const int tid = threadIdx.x;
  const int rr = tid >> 4, c4 = (tid & 15) << 2;
  #pragma unroll
  for (int rep = 0; rep < 4; rep++){
    int r = rr + (rep << 4);
    float4 v = *reinterpret_cast<const float4*>(W + (size_t)(k0 + r)*N + n0 + c4);
    tile[r][c4+0] = f2b(v.x); tile[r][c4+1] = f2b(v.y);
    tile[r][c4+2] = f2b(v.z); tile[r][c4+3] = f2b(v.w);
  }
  __syncthreads();
  const int rn = tid >> 2, kb = (tid & 3) << 4;
  u16 tmp[16];
  #pragma unroll
  for (int j = 0; j < 16; j++) tmp[j] = tile[kb + j][rn];
  ushort4* dst = reinterpret_cast<ushort4*>(Wt + (size_t)(n0 + rn)*K + k0 + kb);
  dst[0] = make_ushort4(tmp[0], tmp[1], tmp[2], tmp[3]);
  dst[1] = make_ushort4(tmp[4], tmp[5], tmp[6], tmp[7]);
  dst[2] = make_ushort4(tmp[8], tmp[9], tmp[10], tmp[11]);
  dst[3] = make_ushort4(tmp[12], tmp[13], tmp[14], tmp[15]);
}

// ---------- LayerNorm: fp32 [rows][1024] -> bf16 ----------
__global__ __launch_bounds__(256) void ln_kernel(const float* __restrict__ X,
                                                 const float* __restrict__ sc,
                                                 const float* __restrict__ sh,
                                                 u16* __restrict__ out){
  const int row = blockIdx.x;
  const int tid = threadIdx.x;
  const float* xr = X + ((size_t)row << 10);
  float4 a = reinterpret_cast<const float4*>(xr)[tid];
  float s = a.x + a.y + a.z + a.w;
  float q = a.x*a.x + a.y*a.y + a.z*a.z + a.w*a.w;
  #pragma unroll
  for (int o = 32; o > 0; o >>= 1){ s += __shfl_xor(s, o); q += __shfl_xor(q, o); }
  __shared__ float red[8];
  const int w = tid >> 6;
  if ((tid & 63) == 0){ red[w] = s; red[4 + w] = q; }
  __syncthreads();
  float S = red[0] + red[1] + red[2] + red[3];
  float Q = red[4] + red[5] + red[6] + red[7];
  float mean = S * (1.0f/1024.0f);
  float var  = Q * (1.0f/1024.0f) - mean*mean;   // population var (ddof=0)
  float inv = rsqrtf(var + 1e-5f);
  float4 gsc = reinterpret_cast<const float4*>(sc)[tid];
  float4 gsh = reinterpret_cast<const float4*>(sh)[tid];
  ushort4 o4;
  o4.x = f2b((a.x - mean)*inv*gsc.x + gsh.x);
  o4.y = f2b((a.y - mean)*inv*gsc.y + gsh.y);
  o4.z = f2b((a.z - mean)*inv*gsc.z + gsh.z);
  o4.w = f2b((a.w - mean)*inv*gsc.w + gsh.w);
  reinterpret_cast<ushort4*>(out + ((size_t)row << 10))[tid] = o4;
}

// ---------- bf16 GEMM: C[M,N] = A[M,K] @ Bt[N,K]^T, 128x128 tile, BK=32 ----------
// XOR swizzle on both LDS tiles: logical 16B-slot s of row r stored at s ^ ((r>>1)&3)
// (staging applies the inverse permutation on the GLOBAL source; LDS dest stays linear).
// EPI 1: QKV scatter to [3][B][H][T][HD] bf16 (N must be 3072)
// EPI 2: +bias[n] +resid[m,n] -> fp32 [M][N]
// EPI 3: gelu_tanh(+bias[n]) -> bf16 [M][N]
template<int EPI>
__global__ __launch_bounds__(256) void gemm_k(const u16* __restrict__ A, const u16* __restrict__ Bt,
                                              const float* __restrict__ bias,
                                              const float* __restrict__ resid,
                                              void* __restrict__ Cv, int M, int N, int K){
  __shared__ __align__(16) u16 As[128*32];
  __shared__ __align__(16) u16 Bs[128*32];
  const int tid = threadIdx.x;
  const int lane = tid & 63;
  const int w = tid >> 6;
  const int wr = w >> 1, wc = w & 1;           // 2x2 waves, each owns 64x64
  const int g = lane >> 4, l15 = lane & 15;
  const int tn0 = blockIdx.x << 7;
  const int tm0 = blockIdx.y << 7;

  f32x4 acc[4][4];
  #pragma unroll
  for (int i = 0; i < 4; i++)
    #pragma unroll
    for (int j = 0; j < 4; j++) acc[i][j] = (f32x4){0.f,0.f,0.f,0.f};

  // staging: 512 16B-chunks per tile, 2 per thread; chunk ch -> row ch>>2, stored slot ch&3
  const int ch0 = tid, ch1 = 256 + tid;
  const int r0 = ch0 >> 2, c0 = (((ch0 & 3) ^ ((r0 >> 1) & 3)) << 3);
  const int r1 = ch1 >> 2, c1 = (((ch1 & 3) ^ ((r1 >> 1) & 3)) << 3);
  const u16* A0 = A  + (size_t)(tm0 + r0)*K + c0;
  const u16* A1 = A  + (size_t)(tm0 + r1)*K + c1;
  const u16* B0 = Bt + (size_t)(tn0 + r0)*K + c0;
  const u16* B1 = Bt + (size_t)(tn0 + r1)*K + c1;
  u16* lA0 = As + ch0*8; u16* lA1 = As + ch1*8;
  u16* lB0 = Bs + ch0*8; u16* lB1 = Bs + ch1*8;

  for (int kt = 0; kt < K; kt += 32){
    gl_lds16(A0 + kt, lA0);
    gl_lds16(A1 + kt, lA1);
    gl_lds16(B0 + kt, lB0);
    gl_lds16(B1 + kt, lB1);
    __syncthreads();                            // compiler emits vmcnt(0) drain here
    s16x8 af[4], bf[4];
    #pragma unroll
    for (int i = 0; i < 4; i++){
      int ra = (wr << 6) + (i << 4) + l15;
      af[i] = *reinterpret_cast<const s16x8*>(As + ra*32 + ((g ^ ((ra >> 1) & 3)) << 3));
    }
    #pragma unroll
    for (int j = 0; j < 4; j++){
      int rb = (wc << 6) + (j << 4) + l15;
      bf[j] = *reinterpret_cast<const s16x8*>(Bs + rb*32 + ((g ^ ((rb >> 1) & 3)) << 3));
    }
    #pragma unroll
    for (int i = 0; i < 4; i++)
      #pragma unroll
      for (int j = 0; j < 4; j++)
        acc[i][j] = __builtin_amdgcn_mfma_f32_16x16x32_bf16(af[i], bf[j], acc[i][j], 0, 0, 0);
    __syncthreads();
  }

  // C/D layout: row = 4*(lane>>4)+rr, col = lane&15 (per frag)
  #pragma unroll
  for (int i = 0; i < 4; i++){
    const int mb = tm0 + (wr << 6) + (i << 4) + (g << 2);
    #pragma unroll
    for (int j = 0; j < 4; j++){
      const int n = tn0 + (wc << 6) + (j << 4) + l15;
      #pragma unroll
      for (int rr = 0; rr < 4; rr++){
        const int m = mb + rr;
        float v = acc[i][j][rr];
        if constexpr (EPI == 1){
          const int sel = n >> 10, nn = n & 1023;
          const int hh = nn >> 6, d = nn & 63;
          ((u16*)Cv)[(size_t)sel*((size_t)M_*D_) +
                     ((((size_t)(m >> 11)*H_ + hh)*T_ + (m & 2047)) << 6) + d] = f2b(v);
        } else if constexpr (EPI == 2){
          ((float*)Cv)[(size_t)m*N + n] = v + bias[n] + resid[(size_t)m*N + n];
        } else {
          float u = v + bias[n];
          float t2 = 0.7978845608f*(u + 0.044715f*u*u*u);
          float e = __expf(2.0f*t2);
          float th = 1.0f - 2.0f/(e + 1.0f);     // stable tanh (inf-safe)
          ((u16*)Cv)[(size_t)m*N + n] = f2b(0.5f*u*(1.0f + th));
        }
      }
    }
  }
}

// ---------- causal flash attention: Q,K,V [B*H][T][64] bf16 -> ctx [B*T][D] bf16 ----------
// grid (qt=T/64, bh=B*H), 4 waves; wave handles 16 q-rows. LDS swizzle: slot s of row r
// stored at s ^ (r&7)  (row stride 128B -> conflict-free-ish reads).
__global__ __launch_bounds__(256) void attn_k(const u16* __restrict__ Qg, const u16* __restrict__ Kg,
                                              const u16* __restrict__ Vg, u16* __restrict__ ctx){
  const int qt = blockIdx.x;
  const int bh = blockIdx.y;
  const int tid = threadIdx.x;
  const int lane = tid & 63;
  const int w = tid >> 6;
  const int g = lane >> 4, l15 = lane & 15;

  __shared__ __align__(16) u16 Qs[64*64];
  __shared__ __align__(16) u16 Ks[64*64];
  __shared__ __align__(16) u16 Vt[64*64];       // V transposed: [d][kr]
  __shared__ __align__(16) u16 Pl[4][16*64];    // per-wave P tile

  const size_t hb = (size_t)bh * ((size_t)T_*HD_);
  const u16* Qh = Qg + hb;
  const u16* Kh = Kg + hb;
  const u16* Vh = Vg + hb;

  // stage Q once (drained by first in-loop barrier)
  {
    int ch = tid;       int r = ch >> 3, c = (((ch & 7) ^ (r & 7)) << 3);
    gl_lds16(Qh + (size_t)(qt*64 + r)*HD_ + c, Qs + ch*8);
    ch = 256 + tid;     r = ch >> 3;  c = (((ch & 7) ^ (r & 7)) << 3);
    gl_lds16(Qh + (size_t)(qt*64 + r)*HD_ + c, Qs + ch*8);
  }

  f32x4 accO[4];
  #pragma unroll
  for (int j = 0; j < 4; j++) accO[j] = (f32x4){0.f,0.f,0.f,0.f};
  float mrow[4] = {-1e30f,-1e30f,-1e30f,-1e30f};
  float lrow[4] = {0.f,0.f,0.f,0.f};

  for (int kt = 0; kt <= qt; ++kt){
    __syncthreads();                            // protect Ks/Vt from previous iter's readers
    {
      int ch = tid;     int r = ch >> 3, c = (((ch & 7) ^ (r & 7)) << 3);
      gl_lds16(Kh + (size_t)(kt*64 + r)*HD_ + c, Ks + ch*8);
      ch = 256 + tid;   r = ch >> 3;  c = (((ch & 7) ^ (r & 7)) << 3);
      gl_lds16(Kh + (size_t)(kt*64 + r)*HD_ + c, Ks + ch*8);
    }
    { // V transpose staging (reg path): thread reads 16 contiguous, scatters to Vt columns
      int kr = tid >> 2, d0 = (tid & 3) << 4;
      const u16* vs = Vh + (size_t)(kt*64 + kr)*HD_ + d0;
      ushort4 a0 = *(const ushort4*)(vs + 0);
      ushort4 a1 = *(const ushort4*)(vs + 4);
      ushort4 a2 = *(const ushort4*)(vs + 8);
      ushort4 a3 = *(const ushort4*)(vs + 12);
      u16 vals[16] = {a0.x,a0.y,a0.z,a0.w, a1.x,a1.y,a1.z,a1.w,
                      a2.x,a2.y,a2.z,a2.w, a3.x,a3.y,a3.z,a3.w};
      #pragma unroll
      for (int j = 0; j < 16; j++){
        int d = d0 + j;
        Vt[d*64 + (((kr >> 3) ^ (d & 7)) << 3) + (kr & 7)] = vals[j];
      }
    }
    __syncthreads();

    // S = Q K^T  (A=Q rows of this wave, B=K rows as K^T cols)
    f32x4 accS[4];
    #pragma unroll
    for (int j = 0; j < 4; j++) accS[j] = (f32x4){0.f,0.f,0.f,0.f};
    s16x8 qa[2];
    #pragma unroll
    for (int kk = 0; kk < 2; kk++){
      int ra = (w << 4) + l15;
      int slot = (kk << 2) + g;
      qa[kk] = *reinterpret_cast<const s16x8*>(Qs + ra*64 + ((slot ^ (ra & 7)) << 3));
    }
    #pragma unroll
    for (int jn = 0; jn < 4; jn++){
      #pragma unroll
      for (int kk = 0; kk < 2; kk++){
        int rb = (jn << 4) + l15;
        int slot = (kk << 2) + g;
        s16x8 kb = *reinterpret_cast<const s16x8*>(Ks + rb*64 + ((slot ^ (rb & 7)) << 3));
        accS[jn] = __builtin_amdgcn_mfma_f32_16x16x32_bf16(qa[kk], kb, accS[jn], 0, 0, 0);
      }
    }

    // scale 1/sqrt(64) + causal mask (diagonal tile only)
    float sv[4][4];
    #pragma unroll
    for (int jn = 0; jn < 4; jn++)
      #pragma unroll
      for (int rr = 0; rr < 4; rr++){
        float xv = accS[jn][rr] * 0.125f;
        if (kt == qt){
          int qrow = (w << 4) + (g << 2) + rr;
          int kcol = (jn << 4) + l15;
          if (kcol > qrow) xv = -1e30f;
        }
        sv[jn][rr] = xv;
      }

    // online softmax: row r = 4g+rr lives in lanes [16g,16g+15]
    float sf[4];
    #pragma unroll
    for (int rr = 0; rr < 4; rr++){
      float t = fmaxf(fmaxf(sv[0][rr], sv[1][rr]), fmaxf(sv[2][rr], sv[3][rr]));
      t = fmaxf(t, __shfl_xor(t, 1));
      t = fmaxf(t, __shfl_xor(t, 2));
      t = fmaxf(t, __shfl_xor(t, 4));
      t = fmaxf(t, __shfl_xor(t, 8));
      float mn = fmaxf(mrow[rr], t);
      sf[rr] = __expf(mrow[rr] - mn);
      mrow[rr] = mn;
    }
    float tsum[4] = {0.f,0.f,0.f,0.f};
    #pragma unroll
    for (int jn = 0; jn < 4; jn++)
      #pragma unroll
      for (int rr = 0; rr < 4; rr++){
        float pv = __expf(sv[jn][rr] - mrow[rr]);
        tsum[rr] += pv;
        int prow = (g << 2) + rr;
        int pcol = (jn << 4) + l15;
        Pl[w][prow*64 + (((pcol >> 3) ^ (prow & 7)) << 3) + (pcol & 7)] = f2b(pv);
      }
    #pragma unroll
    for (int rr = 0; rr < 4; rr++){
      float t = tsum[rr];
      t += __shfl_xor(t, 1);
      t += __shfl_xor(t, 2);
      t += __shfl_xor(t, 4);
      t += __shfl_xor(t, 8);
      lrow[rr] = lrow[rr]*sf[rr] + t;
      #pragma unroll
      for (int jn = 0; jn < 4; jn++) accO[jn][rr] *= sf[rr];
    }
    __syncthreads();                            // make P (cross-lane) + keep waves in lockstep

    // O += P V   (A=P from Pl, B=V via Vt)
    #pragma unroll
    for (int kk = 0; kk < 2; kk++){
      int slot = (kk << 2) + g;
      int pr = l15;
      s16x8 pa = *reinterpret_cast<const s16x8*>(&Pl[w][pr*64 + ((slot ^ (pr & 7)) << 3)]);
      #pragma unroll
      for (int jn = 0; jn < 4; jn++){
        int vd = (jn << 4) + l15;
        s16x8 vbf = *reinterpret_cast<const s16x8*>(Vt + vd*64 + ((slot ^ (vd & 7)) << 3));
        accO[jn] = __builtin_amdgcn_mfma_f32_16x16x32_bf16(pa, vbf, accO[jn], 0, 0, 0);
      }
    }
  }

  // epilogue: O/l -> ctx[(b*T+q)*D + h*64 + d]
  const int b = bh >> 4, hh = bh & 15;
  #pragma unroll
  for (int rr = 0; rr < 4; rr++){
    float inv = 1.0f / lrow[rr];
    int qrow = qt*64 + (w << 4) + (g << 2) + rr;
    size_t rowbase = ((size_t)(b*T_ + qrow) << 10) + ((size_t)hh << 6);
    #pragma unroll
    for (int jn = 0; jn < 4; jn++){
      int d = (jn << 4) + l15;
      ctx[rowbase + d] = f2b(accO[jn][rr] * inv);
    }
  }
}

// ---------- launch ----------
extern "C" void kernel_launch(void* const* d_in, const int* in_sizes, int n_in,
                              void* d_out, int out_size, void* d_ws, size_t ws_size,
                              hipStream_t stream){
  (void)in_sizes; (void)n_in; (void)out_size; (void)ws_size;
  const float* x    = (const float*)d_in[0];
  const float* wq   = (const float*)d_in[1];
  const float* wk   = (const float*)d_in[2];
  const float* wv   = (const float*)d_in[3];
  const float* wo   = (const float*)d_in[4];
  const float* bo   = (const float*)d_in[5];
  const float* ln1s = (const float*)d_in[6];
  const float* ln1b = (const float*)d_in[7];
  const float* ln2s = (const float*)d_in[8];
  const float* ln2b = (const float*)d_in[9];
  const float* w1   = (const float*)d_in[10];
  const float* b1   = (const float*)d_in[11];
  const float* w2   = (const float*)d_in[12];
  const float* b2   = (const float*)d_in[13];
  float* out = (float*)d_out;

  char* p = (char*)d_ws;
  u16*  wqkvT = (u16*)p;  p += (size_t)3*D_*D_*2;   // [3072][1024] (wqT|wkT|wvT)
  u16*  woT   = (u16*)p;  p += (size_t)D_*D_*2;     // [1024][1024]
  u16*  w1T   = (u16*)p;  p += (size_t)D_*DFF_*2;   // [4096][1024]
  u16*  w2T   = (u16*)p;  p += (size_t)DFF_*D_*2;   // [1024][4096]
  u16*  h     = (u16*)p;  p += (size_t)M_*D_*2;
  u16*  qb    = (u16*)p;  p += (size_t)M_*D_*2;     // [B][H][T][64] — qb,kb,vb contiguous
  u16*  kb    = (u16*)p;  p += (size_t)M_*D_*2;
  u16*  vb    = (u16*)p;  p += (size_t)M_*D_*2;
  u16*  ctx   = (u16*)p;  p += (size_t)M_*D_*2;
  float* x1   = (float*)p; p += (size_t)M_*D_*4;
  u16*  h2    = (u16*)p;  p += (size_t)M_*D_*2;
  u16*  ff1   = (u16*)p;  p += (size_t)M_*DFF_*2;
  (void)kb; (void)vb;  // addressed via EPI-1 scatter offsets from qb

  dim3 blk(256);
  wconv<<<dim3(16,16), blk, 0, stream>>>(wq, wqkvT + 0*(size_t)D_*D_, D_, D_);
  wconv<<<dim3(16,16), blk, 0, stream>>>(wk, wqkvT + 1*(size_t)D_*D_, D_, D_);
  wconv<<<dim3(16,16), blk, 0, stream>>>(wv, wqkvT + 2*(size_t)D_*D_, D_, D_);
  wconv<<<dim3(16,16), blk, 0, stream>>>(wo, woT, D_, D_);
  wconv<<<dim3(16,64), blk, 0, stream>>>(w1, w1T, D_, DFF_);
  wconv<<<dim3(64,16), blk, 0, stream>>>(w2, w2T, DFF_, D_);

  ln_kernel<<<M_, blk, 0, stream>>>(x, ln1s, ln1b, h);
  gemm_k<1><<<dim3(24,32), blk, 0, stream>>>(h, wqkvT, nullptr, nullptr, qb, M_, 3*D_, D_);
  attn_k<<<dim3(32,32), blk, 0, stream>>>(qb, qb + (size_t)M_*D_, qb + 2*(size_t)M_*D_, ctx);
  gemm_k<2><<<dim3(8,32),  blk, 0, stream>>>(ctx, woT, bo, x, x1, M_, D_, D_);
  ln_kernel<<<M_, blk, 0, stream>>>(x1, ln2s, ln2b, h2);
  gemm_k<3><<<dim3(32,32), blk, 0, stream>>>(h2, w1T, b1, nullptr, ff1, M_, DFF_, D_);
  gemm_k<2><<<dim3(8,32),  blk, 0, stream>>>(ff1, w2T, b2, x1, out, M_, D_, DFF_);
}